// Round 1
// baseline (318.931 us; speedup 1.0000x reference)
//
#include <hip/hip_runtime.h>
#include <hip/hip_bf16.h>

#define A_N   2048
#define D_N   64
#define FL_N  12
#define KTOT  (A_N * FL_N)          // 24576
#define S_SPLIT 24
#define KCHUNK (KTOT / S_SPLIT)     // 1024

typedef __attribute__((ext_vector_type(8))) short bf16x8;  // 8 bf16 = 4 VGPRs
typedef __attribute__((ext_vector_type(4))) short bf16x4;  // 8 B
typedef __attribute__((ext_vector_type(4))) float f32x4;

__device__ __forceinline__ short f2bf(float f) {
  union { __hip_bfloat16 b; short s; } u;
  u.b = __float2bfloat16(f);
  return u.s;
}

// ---------- one-time prep kernels ----------

// P2[o][f][d] = pf[o,f,d] * bf[o,f,0]  (bf16)
__global__ void k_p2(const float* __restrict__ pf, const float* __restrict__ bf,
                     short* __restrict__ P2) {
  int idx = blockIdx.x * 256 + threadIdx.x;
  if (idx >= D_N * FL_N * D_N) return;
  int f = (idx >> 6) % FL_N;
  int o = idx / (D_N * FL_N);
  P2[idx] = f2bf(pf[idx] * bf[(o * FL_N + f) * 3]);
}

// bond[a][o] = sum_f bp[a,f,0]*bf[o,f,1] + bp[a,f,1]*bf[o,f,2]
__global__ void k_bond(const float* __restrict__ bp, const float* __restrict__ bf,
                       float* __restrict__ bond) {
  int t = threadIdx.x;
  int o = t & 63;
  int a = blockIdx.x * 4 + (t >> 6);
  float s = 0.f;
#pragma unroll
  for (int f = 0; f < FL_N; ++f) {
    s += bp[(a * FL_N + f) * 2 + 0] * bf[(o * FL_N + f) * 3 + 1]
       + bp[(a * FL_N + f) * 2 + 1] * bf[(o * FL_N + f) * 3 + 2];
  }
  bond[a * D_N + o] = s;
}

// f32 -> bf16 copy (exactly 131072 elements, grid 512 x 256)
__global__ void k_cvt(const float* __restrict__ x, short* __restrict__ xb) {
  int i = blockIdx.x * 256 + threadIdx.x;
  xb[i] = f2bf(x[i]);
}

// ---------- per-conv kernels ----------

// Bt[o][k*12+f] = sum_d h[k,d] * P2[o,f,d]
// Small GEMM via MFMA 16x16x32: M=o(16/wave-tile), N=k(16/block-tile), K=d(64).
// grid = 128 blocks (k-tiles of 16), 256 threads = 4 waves (wave w -> o-tile w).
__global__ void k_prep(const short* __restrict__ hb, const short* __restrict__ P2,
                       short* __restrict__ Bt) {
  int lane = threadIdx.x & 63;
  int w    = threadIdx.x >> 6;      // o-tile 0..3
  int l15  = lane & 15;
  int grp  = lane >> 4;
  int k0   = blockIdx.x * 16;

  // B-operand (h^T): n = l15 -> k, k-elems -> d = grp*8 + i (+32 second half)
  const short* hrow = hb + (k0 + l15) * D_N + grp * 8;
  bf16x8 h0 = *(const bf16x8*)(hrow);
  bf16x8 h1 = *(const bf16x8*)(hrow + 32);

  const short* prow = P2 + (w * 16 + l15) * (FL_N * D_N) + grp * 8;

  f32x4 acc[FL_N];
#pragma unroll
  for (int f = 0; f < FL_N; ++f) {
    bf16x8 p0 = *(const bf16x8*)(prow + f * D_N);
    bf16x8 p1 = *(const bf16x8*)(prow + f * D_N + 32);
    f32x4 c = {0.f, 0.f, 0.f, 0.f};
    c = __builtin_amdgcn_mfma_f32_16x16x32_bf16(p0, h0, c, 0, 0, 0);
    c = __builtin_amdgcn_mfma_f32_16x16x32_bf16(p1, h1, c, 0, 0, 0);
    acc[f] = c;
  }

  // D layout: row(o) = grp*4 + r (+w*16), col(k) = l15 (+k0)
#pragma unroll
  for (int r = 0; r < 4; ++r) {
    int o = w * 16 + grp * 4 + r;
    int k = k0 + l15;
    short ov[FL_N];
#pragma unroll
    for (int f = 0; f < FL_N; ++f) ov[f] = f2bf(acc[f][r]);
    short* dst = Bt + (size_t)o * KTOT + k * FL_N;
    *(bf16x4*)(dst)     = *(const bf16x4*)(ov);
    *(bf16x4*)(dst + 4) = *(const bf16x4*)(ov + 4);
    *(bf16x4*)(dst + 8) = *(const bf16x4*)(ov + 8);
  }
}

// Big GEMM: part[kc][a][o] = sum_{j in chunk} conn[a][j] * Bt[o][j]
// grid = (32 m-tiles, S_SPLIT k-chunks), 256 threads = 4 waves (wave w -> 16 rows).
__global__ __launch_bounds__(256) void k_gemm(const float* __restrict__ conn,
                                              const short* __restrict__ Bt,
                                              float* __restrict__ part) {
  int mt   = blockIdx.x;
  int kc   = blockIdx.y;
  int lane = threadIdx.x & 63;
  int w    = threadIdx.x >> 6;
  int l15  = lane & 15;
  int grp  = lane >> 4;

  int row = mt * 64 + w * 16 + l15;
  const float* ap = conn + (size_t)row * KTOT + kc * KCHUNK + grp * 8;
  const short* bp = Bt + (size_t)l15 * KTOT + kc * KCHUNK + grp * 8;

  f32x4 acc0 = {0,0,0,0}, acc1 = {0,0,0,0}, acc2 = {0,0,0,0}, acc3 = {0,0,0,0};

#pragma unroll 4
  for (int ks = 0; ks < KCHUNK / 32; ++ks) {
    f32x4 a0 = *(const f32x4*)(ap);
    f32x4 a1 = *(const f32x4*)(ap + 4);
    ap += 32;

    bf16x8 b0 = *(const bf16x8*)(bp);
    bf16x8 b1 = *(const bf16x8*)(bp + (size_t)16 * KTOT);
    bf16x8 b2 = *(const bf16x8*)(bp + (size_t)32 * KTOT);
    bf16x8 b3 = *(const bf16x8*)(bp + (size_t)48 * KTOT);
    bp += 32;

    bf16x8 af;
    af[0] = f2bf(a0[0]); af[1] = f2bf(a0[1]); af[2] = f2bf(a0[2]); af[3] = f2bf(a0[3]);
    af[4] = f2bf(a1[0]); af[5] = f2bf(a1[1]); af[6] = f2bf(a1[2]); af[7] = f2bf(a1[3]);

    acc0 = __builtin_amdgcn_mfma_f32_16x16x32_bf16(af, b0, acc0, 0, 0, 0);
    acc1 = __builtin_amdgcn_mfma_f32_16x16x32_bf16(af, b1, acc1, 0, 0, 0);
    acc2 = __builtin_amdgcn_mfma_f32_16x16x32_bf16(af, b2, acc2, 0, 0, 0);
    acc3 = __builtin_amdgcn_mfma_f32_16x16x32_bf16(af, b3, acc3, 0, 0, 0);
  }

  float* p = part + (size_t)kc * (A_N * D_N);
  int abase = mt * 64 + w * 16 + grp * 4;
#pragma unroll
  for (int r = 0; r < 4; ++r) {
    float* pr = p + (size_t)(abase + r) * D_N + l15;
    pr[0]  = acc0[r];
    pr[16] = acc1[r];
    pr[32] = acc2[r];
    pr[48] = acc3[r];
  }
}

// reduce partials + bond (+x) -> relu -> hb (bf16) and optional f32 out
__global__ void k_reduce(const float* __restrict__ part, const float* __restrict__ bond,
                         const float* __restrict__ x, int addx,
                         short* __restrict__ hb, float* __restrict__ fout) {
  int i = blockIdx.x * 256 + threadIdx.x;  // 131072 total
  float s = bond[i];
#pragma unroll
  for (int si = 0; si < S_SPLIT; ++si) s += part[(size_t)si * (A_N * D_N) + i];
  if (addx) s += x[i];
  s = fmaxf(s, 0.f);
  hb[i] = f2bf(s);
  if (fout) fout[i] = s;
}

// ---------- launch ----------

extern "C" void kernel_launch(void* const* d_in, const int* in_sizes, int n_in,
                              void* d_out, int out_size, void* d_ws, size_t ws_size,
                              hipStream_t stream) {
  const float* x    = (const float*)d_in[0];
  const float* conn = (const float*)d_in[1];
  const float* bprp = (const float*)d_in[2];
  const float* pf0  = (const float*)d_in[3];
  const float* bf0  = (const float*)d_in[4];
  const float* pf1  = (const float*)d_in[5];
  const float* bf1  = (const float*)d_in[6];
  float* out = (float*)d_out;

  char* ws = (char*)d_ws;
  size_t off = 0;
  short* Bt   = (short*)(ws + off); off += (size_t)D_N * KTOT * 2;          // 3 MB
  float* part = (float*)(ws + off); off += (size_t)S_SPLIT * A_N * D_N * 4; // 12 MB
  short* hb   = (short*)(ws + off); off += (size_t)A_N * D_N * 2;
  short* xb   = (short*)(ws + off); off += (size_t)A_N * D_N * 2;
  float* bond0 = (float*)(ws + off); off += (size_t)A_N * D_N * 4;
  float* bond1 = (float*)(ws + off); off += (size_t)A_N * D_N * 4;
  short* P2_0 = (short*)(ws + off); off += (size_t)D_N * FL_N * D_N * 2;
  short* P2_1 = (short*)(ws + off); off += (size_t)D_N * FL_N * D_N * 2;

  // one-time prep
  k_p2<<<192, 256, 0, stream>>>(pf0, bf0, P2_0);
  k_p2<<<192, 256, 0, stream>>>(pf1, bf1, P2_1);
  k_bond<<<512, 256, 0, stream>>>(bprp, bf0, bond0);
  k_bond<<<512, 256, 0, stream>>>(bprp, bf1, bond1);
  k_cvt<<<512, 256, 0, stream>>>(x, xb);

  // conv chain: c=0: relu(conv(x)); c=1: relu(conv+x); c=2: relu(conv); c=3: relu(conv+x)->out
  for (int c = 0; c < 4; ++c) {
    const short* hin = (c == 0) ? xb : hb;
    const short* P2  = (c < 2) ? P2_0 : P2_1;
    const float* bnd = (c < 2) ? bond0 : bond1;
    int addx = (c == 1 || c == 3);
    float* fout = (c == 3) ? out : nullptr;

    k_prep<<<128, 256, 0, stream>>>(hin, P2, Bt);
    k_gemm<<<dim3(32, S_SPLIT), 256, 0, stream>>>(conn, Bt, part);
    k_reduce<<<512, 256, 0, stream>>>(part, bnd, x, addx, hb, fout);
  }
}